// Round 13
// baseline (196.495 us; speedup 1.0000x reference)
//
#include <hip/hip_runtime.h>

typedef unsigned short u16;
typedef unsigned int u32;
typedef __bf16 bf16x8 __attribute__((ext_vector_type(8)));
typedef float f32x4 __attribute__((ext_vector_type(4)));
typedef unsigned short u16x8 __attribute__((ext_vector_type(8)));
typedef unsigned short u16x4 __attribute__((ext_vector_type(4)));
typedef float f4 __attribute__((ext_vector_type(4)));

__device__ __forceinline__ float bf2f(u16 u) {
    union { unsigned int i; float f; } c; c.i = ((unsigned int)u) << 16; return c.f;
}
__device__ __forceinline__ u16 f2bf(float f) {
    union { float f; unsigned int i; } c; c.f = f;
    unsigned int r = c.i + 0x7FFFu + ((c.i >> 16) & 1u);  // RNE
    return (u16)(r >> 16);
}
__device__ __forceinline__ u16 f2bf_rtz(float f) {   // truncate: 1 VALU op
    union { float f; unsigned int i; } c; c.f = f;
    return (u16)(c.i >> 16);
}
__device__ __forceinline__ float fast_exp2(float x) {
#if __has_builtin(__builtin_amdgcn_exp2f)
    return __builtin_amdgcn_exp2f(x);   // raw v_exp_f32, no OCML fixup
#else
    return exp2f(x);
#endif
}
// async global->LDS, 16B/lane; LDS dest = wave-uniform base + lane*16
__device__ __forceinline__ void async16(const void* g, void* l) {
    __builtin_amdgcn_global_load_lds(
        (const __attribute__((address_space(1))) u32*)g,
        (__attribute__((address_space(3))) u32*)l, 16, 0, 0);
}

// ---------------------------------------------------------------------------
// Merged prepass (one launch) — measured win (R11/R12):
//  blocks [0,2048):    x f32 -> bf16 Xb (8 elems/thread)
//  blocks [2048,5120): transpose+cast qkv_w [1024][3072] -> qwT [3072][1024]
//  blocks [5120,6144): transpose+cast proj_w [1024][1024] -> pwT [1024][1024]
// ---------------------------------------------------------------------------
__global__ __launch_bounds__(256) void prep(
    const float* __restrict__ X, u16* __restrict__ Xb,
    const float* __restrict__ qkv_w, u16* __restrict__ qwT,
    const float* __restrict__ proj_w, u16* __restrict__ pwT)
{
    __shared__ float tile[32][33];
    const int blk = blockIdx.x;
    const int t = threadIdx.x;
    if (blk < 2048) {
        const size_t i = ((size_t)blk * 256 + t) * 8;
        u16x8 h;
        #pragma unroll
        for (int e = 0; e < 8; ++e) h[e] = f2bf(X[i + e]);
        *(u16x8*)&Xb[i] = h;
        return;
    }
    const float* W; u16* Th; int K, N, bx, by;
    if (blk < 5120) {
        W = qkv_w; Th = qwT; K = 1024; N = 3072;
        bx = (blk - 2048) % 96; by = (blk - 2048) / 96;
    } else {
        W = proj_w; Th = pwT; K = 1024; N = 1024;
        bx = (blk - 5120) % 32; by = (blk - 5120) / 32;
    }
    const int bk = by * 32, bn = bx * 32;
    const int tx = t & 31, ty = t >> 5;  // 32 x 8
    #pragma unroll
    for (int r = ty; r < 32; r += 8)
        tile[r][tx] = W[(size_t)(bk + r) * N + bn + tx];
    __syncthreads();
    #pragma unroll
    for (int r = ty; r < 32; r += 8)
        Th[(size_t)(bn + r) * K + bk + tx] = f2bf(tile[tx][r]);
}

// ---------------------------------------------------------------------------
// QKV GEMM (128x128 tile, BK=32, m97 staging) with fused bias + per-head
// RMSNorm -> Qb/Kb bf16 [bh][n][64] (q gets 1/8*log2e folded in) and
// V transpose -> Vt bf16 [bh][d][n].
// C/D layout: col = lane&15, row = (lane>>4)*4 + reg (verified m89/m91).
// ---------------------------------------------------------------------------
__global__ __launch_bounds__(256) void gemm_qkv(
    const u16* __restrict__ AH, const u16* __restrict__ BH,
    const float* __restrict__ bias,
    u16* __restrict__ Qb, u16* __restrict__ Kb, u16* __restrict__ Vt,
    const float* __restrict__ qw, const float* __restrict__ kw)
{
    const int K = 1024;
    __shared__ __align__(16) u16 AhT[128 * 32];
    __shared__ __align__(16) u16 BhT[128 * 32];
    const int t = threadIdx.x;
    const int bm = blockIdx.y * 128, bn = blockIdx.x * 128;
    const int wave = t >> 6, lane = t & 63;
    const int wm = (wave >> 1) * 64, wn = (wave & 1) * 64;
    const int l15 = lane & 15, quad = lane >> 4;
    const int srow = lane >> 2, scol = (lane & 3) * 8;

    f32x4 acc[4][4];
    const f32x4 zero = {0.0f, 0.0f, 0.0f, 0.0f};
    #pragma unroll
    for (int i = 0; i < 4; ++i)
        #pragma unroll
        for (int j = 0; j < 4; ++j) acc[i][j] = zero;

    for (int k0 = 0; k0 < K; k0 += 32) {
        #pragma unroll
        for (int rr = 0; rr < 2; ++rr) {
            const int r0 = (rr * 4 + wave) * 16;
            const size_t ga = (size_t)(bm + r0 + srow) * K + k0 + scol;
            const size_t gb = (size_t)(bn + r0 + srow) * K + k0 + scol;
            async16(&AH[ga], &AhT[r0 * 32]);
            async16(&BH[gb], &BhT[r0 * 32]);
        }
        __syncthreads();
        bf16x8 ah[4], bh[4];
        #pragma unroll
        for (int i = 0; i < 4; ++i)
            ah[i] = *(const bf16x8*)&AhT[(wm + i * 16 + l15) * 32 + quad * 8];
        #pragma unroll
        for (int j = 0; j < 4; ++j)
            bh[j] = *(const bf16x8*)&BhT[(wn + j * 16 + l15) * 32 + quad * 8];
        #pragma unroll
        for (int i = 0; i < 4; ++i)
            #pragma unroll
            for (int j = 0; j < 4; ++j)
                acc[i][j] = __builtin_amdgcn_mfma_f32_16x16x32_bf16(
                    ah[i], bh[j], acc[i][j], 0, 0, 0);
        __syncthreads();
    }

    // wave's 64-col group = one (section, head) pair
    const int gc0 = bn + wn;
    const int sec = gc0 >> 10;              // 0=q, 1=k, 2=v
    const int h = (gc0 & 1023) >> 6;
    const int b = bm >> 11;
    const int bhd = b * 16 + h;
    float bv[4], wj[4];
    #pragma unroll
    for (int j = 0; j < 4; ++j) {
        const int d = j * 16 + l15;
        bv[j] = bias[gc0 + d];
        wj[j] = (sec == 2) ? 0.0f : (sec ? kw[d] : qw[d] * 0.18033688011f);
    }
    if (sec < 2) {
        u16* dst = sec ? Kb : Qb;
        #pragma unroll
        for (int i = 0; i < 4; ++i) {
            float val[4][4];
            float ss[4] = {0.0f, 0.0f, 0.0f, 0.0f};
            #pragma unroll
            for (int j = 0; j < 4; ++j)
                #pragma unroll
                for (int r = 0; r < 4; ++r) {
                    val[j][r] = acc[i][j][r] + bv[j];
                    ss[r] += val[j][r] * val[j][r];
                }
            #pragma unroll
            for (int r = 0; r < 4; ++r) {
                #pragma unroll
                for (int m = 1; m < 16; m <<= 1)
                    ss[r] += __shfl_xor(ss[r], m, 64);
                const float nrm = rsqrtf(ss[r] * 0.015625f + 1e-6f);
                const int n = (bm + wm + i * 16 + quad * 4 + r) & 2047;
                const size_t rowb = ((size_t)bhd * 2048 + n) * 64;
                #pragma unroll
                for (int j = 0; j < 4; ++j)
                    dst[rowb + j * 16 + l15] = f2bf(val[j][r] * nrm * wj[j]);
            }
        }
    } else {
        #pragma unroll
        for (int i = 0; i < 4; ++i) {
            const int n0 = (bm + wm + i * 16 + quad * 4) & 2047;
            #pragma unroll
            for (int j = 0; j < 4; ++j) {
                const int d = j * 16 + l15;
                u16x4 pk;
                #pragma unroll
                for (int r = 0; r < 4; ++r)
                    pk[r] = f2bf(acc[i][j][r] + bv[j]);
                *(u16x4*)&Vt[((size_t)bhd * 64 + d) * 2048 + n0] = pk;
            }
        }
    }
}

// ---------------------------------------------------------------------------
// Proj GEMM, 64x128 tile for 512-block occupancy. Wave = 64 rows x 32 cols.
// out f32 = Attn @ pwT^T + bias.
// ---------------------------------------------------------------------------
__global__ __launch_bounds__(256) void gemm_proj(
    const u16* __restrict__ AH, const u16* __restrict__ BH,
    const float* __restrict__ bias, float* __restrict__ C)
{
    const int N = 1024, K = 1024;
    __shared__ __align__(16) u16 AhT[64 * 32];
    __shared__ __align__(16) u16 BhT[128 * 32];
    const int t = threadIdx.x;
    const int bm = blockIdx.y * 64, bn = blockIdx.x * 128;
    const int wave = t >> 6, lane = t & 63;
    const int l15 = lane & 15, quad = lane >> 4;
    const int srow = lane >> 2, scol = (lane & 3) * 8;

    f32x4 acc[4][2];
    const f32x4 zero = {0.0f, 0.0f, 0.0f, 0.0f};
    #pragma unroll
    for (int i = 0; i < 4; ++i)
        #pragma unroll
        for (int j = 0; j < 2; ++j) acc[i][j] = zero;

    for (int k0 = 0; k0 < K; k0 += 32) {
        {
            const int r0 = wave * 16;
            async16(&AH[(size_t)(bm + r0 + srow) * K + k0 + scol],
                    &AhT[r0 * 32]);
        }
        #pragma unroll
        for (int cc = 0; cc < 2; ++cc) {
            const int r0 = (wave * 2 + cc) * 16;
            async16(&BH[(size_t)(bn + r0 + srow) * K + k0 + scol],
                    &BhT[r0 * 32]);
        }
        __syncthreads();
        bf16x8 ah[4], bh[2];
        #pragma unroll
        for (int i = 0; i < 4; ++i)
            ah[i] = *(const bf16x8*)&AhT[(i * 16 + l15) * 32 + quad * 8];
        #pragma unroll
        for (int j = 0; j < 2; ++j)
            bh[j] = *(const bf16x8*)
                &BhT[(wave * 32 + j * 16 + l15) * 32 + quad * 8];
        #pragma unroll
        for (int i = 0; i < 4; ++i)
            #pragma unroll
            for (int j = 0; j < 2; ++j)
                acc[i][j] = __builtin_amdgcn_mfma_f32_16x16x32_bf16(
                    ah[i], bh[j], acc[i][j], 0, 0, 0);
        __syncthreads();
    }

    #pragma unroll
    for (int j = 0; j < 2; ++j) {
        const int col = bn + wave * 32 + j * 16 + l15;
        const float bv = bias[col];
        #pragma unroll
        for (int i = 0; i < 4; ++i) {
            const int row = bm + i * 16 + quad * 4;
            #pragma unroll
            for (int r = 0; r < 4; ++r)
                C[(size_t)(row + r) * N + col] = acc[i][j][r] + bv;
        }
    }
}

// ---------------------------------------------------------------------------
// MFMA flash attention v6. Block = 4 waves x 32 q-rows = 128-row Q tile.
// vs R12 (59.5 us): (1) K/V LDS double-buffered, ONE __syncthreads per iter
// whose vmcnt drain waits a DMA issued a FULL iteration earlier (latency
// covered by compute) — R12 had two barriers/iter with uncovered drains;
// (2) Q frags loaded directly from global (Qlds removed, LDS 50.5 KB,
// 3 blocks/CU unchanged). S^T = K Q^T operand swap (b64 P writes), static-
// max softmax (q pre-scaled by 1/8*log2e), swizzled DMA staging.
// ---------------------------------------------------------------------------
__global__ __launch_bounds__(256) void flash_attn_mfma(
    const u16* __restrict__ Qb, const u16* __restrict__ Kb,
    const u16* __restrict__ Vt, u16* __restrict__ Attn)
{
    __shared__ __align__(16) u16 Klds[2 * 64 * 64];  // swizzled [key][d], dbuf
    __shared__ __align__(16) u16 Vlds[2 * 64 * 64];  // swizzled [d][key], dbuf
    __shared__ __align__(16) u16 Plds[128][72];      // [q][key], b64 writes
    __shared__ float Lbuf[128];

    const int t = threadIdx.x;
    const int qt = blockIdx.x;     // 0..15 (128-row Q tiles)
    const int bh = blockIdx.y;     // 0..31
    const int n0 = qt * 128;
    const size_t kbase = (size_t)bh * 2048 * 64;
    const size_t vbase = (size_t)bh * 64 * 2048;
    const int wave = t >> 6, lane = t & 63;
    const int l15 = lane & 15, quad = lane >> 4;
    const int srow8 = lane >> 3;
    const int sgrp = lane & 7;

    // Q frags direct from global (B-operand: col=q, k=d); loaded once.
    bf16x8 qf[2][2];
    #pragma unroll
    for (int qs = 0; qs < 2; ++qs) {
        const size_t qrow =
            ((size_t)bh * 2048 + n0 + wave * 32 + qs * 16 + l15) * 64;
        qf[qs][0] = *(const bf16x8*)&Qb[qrow + quad * 8];
        qf[qs][1] = *(const bf16x8*)&Qb[qrow + 32 + quad * 8];
    }

    int kofs[4][2];
    #pragma unroll
    for (int nt = 0; nt < 4; ++nt) {
        const int row = nt * 16 + l15;
        kofs[nt][0] = row * 64 + ((quad ^ (row & 7)) * 8);
        kofs[nt][1] = row * 64 + (((quad + 4) ^ (row & 7)) * 8);
    }

    f32x4 o[2][4];
    const f32x4 zero = {0.0f, 0.0f, 0.0f, 0.0f};
    #pragma unroll
    for (int qs = 0; qs < 2; ++qs)
        #pragma unroll
        for (int dt = 0; dt < 4; ++dt) o[qs][dt] = zero;
    float lsum[2] = {0.0f, 0.0f};

    // prologue: stage K/V tile 0 into buffer 0
    #pragma unroll
    for (int cc = 0; cc < 2; ++cc) {
        const int r0 = (wave + cc * 4) * 8;
        const int row = r0 + srow8;
        const int gg = sgrp ^ (row & 7);
        async16(&Kb[kbase + (size_t)row * 64 + gg * 8], &Klds[r0 * 64]);
        async16(&Vt[vbase + (size_t)row * 2048 + gg * 8], &Vlds[r0 * 64]);
    }

    for (int kt = 0; kt < 32; ++kt) {
        // Single barrier: drains the DMA for buf[kt&1] (issued one full
        // iteration ago) and fences prior-iter reads of buf[(kt+1)&1].
        __syncthreads();
        if (kt + 1 < 32) {   // prefetch next tile into the other buffer
            const int nb = ((kt + 1) & 1) * 4096;
            #pragma unroll
            for (int cc = 0; cc < 2; ++cc) {
                const int r0 = (wave + cc * 4) * 8;
                const int row = r0 + srow8;
                const int gg = sgrp ^ (row & 7);
                async16(&Kb[kbase + (size_t)((kt + 1) * 64 + row) * 64 + gg * 8],
                        &Klds[nb + r0 * 64]);
                async16(&Vt[vbase + (size_t)row * 2048 + (kt + 1) * 64 + gg * 8],
                        &Vlds[nb + r0 * 64]);
            }
        }
        const int cb = (kt & 1) * 4096;

        // S^T = K Q^T : lane gets s[qs][nt][r] = S[q=l15][key=nt*16+quad*4+r]
        f32x4 s[2][4];
        #pragma unroll
        for (int nt = 0; nt < 4; ++nt) {
            bf16x8 kf0 = *(const bf16x8*)&Klds[cb + kofs[nt][0]];
            bf16x8 kf1 = *(const bf16x8*)&Klds[cb + kofs[nt][1]];
            #pragma unroll
            for (int qs = 0; qs < 2; ++qs) {
                s[qs][nt] = zero;
                s[qs][nt] = __builtin_amdgcn_mfma_f32_16x16x32_bf16(
                    kf0, qf[qs][0], s[qs][nt], 0, 0, 0);
                s[qs][nt] = __builtin_amdgcn_mfma_f32_16x16x32_bf16(
                    kf1, qf[qs][1], s[qs][nt], 0, 0, 0);
            }
        }

        // p = exp2(s); lsum += p; pack 4 keys -> one b64 LDS write
        #pragma unroll
        for (int qs = 0; qs < 2; ++qs) {
            const int prow = wave * 32 + qs * 16 + l15;
            #pragma unroll
            for (int nt = 0; nt < 4; ++nt) {
                u16x4 pk;
                #pragma unroll
                for (int r = 0; r < 4; ++r) {
                    const float p = fast_exp2(s[qs][nt][r]);
                    lsum[qs] += p;
                    pk[r] = f2bf_rtz(p);
                }
                *(u16x4*)&Plds[prow][nt * 16 + quad * 4] = pk;
            }
        }

        // read P back in A-layout (in-wave DS order guarantees visibility)
        bf16x8 pf[2][2];
        #pragma unroll
        for (int qs = 0; qs < 2; ++qs) {
            const int prow = wave * 32 + qs * 16 + l15;
            pf[qs][0] = *(const bf16x8*)&Plds[prow][quad * 8];
            pf[qs][1] = *(const bf16x8*)&Plds[prow][quad * 8 + 32];
        }

        // O += P V : 2 qsub x 4 d-tiles x 2 ksteps
        #pragma unroll
        for (int dt = 0; dt < 4; ++dt) {
            bf16x8 vf0 = *(const bf16x8*)&Vlds[cb + kofs[dt][0]];
            bf16x8 vf1 = *(const bf16x8*)&Vlds[cb + kofs[dt][1]];
            #pragma unroll
            for (int qs = 0; qs < 2; ++qs) {
                o[qs][dt] = __builtin_amdgcn_mfma_f32_16x16x32_bf16(
                    pf[qs][0], vf0, o[qs][dt], 0, 0, 0);
                o[qs][dt] = __builtin_amdgcn_mfma_f32_16x16x32_bf16(
                    pf[qs][1], vf1, o[qs][dt], 0, 0, 0);
            }
        }
    }

    // lsum: per-lane partial for q=l15 over this quad's keys.
    // Reduce across quads (xor 16, 32), broadcast via Lbuf to O rows.
    #pragma unroll
    for (int qs = 0; qs < 2; ++qs) {
        lsum[qs] += __shfl_xor(lsum[qs], 16, 64);
        lsum[qs] += __shfl_xor(lsum[qs], 32, 64);
        if (quad == 0) Lbuf[wave * 32 + qs * 16 + l15] = lsum[qs];
    }
    const size_t obase =
        ((size_t)(bh >> 4) * 2048 + n0) * 1024 + (bh & 15) * 64;
    #pragma unroll
    for (int qs = 0; qs < 2; ++qs)
        #pragma unroll
        for (int r = 0; r < 4; ++r) {
            const float inv =
                1.0f / Lbuf[wave * 32 + qs * 16 + quad * 4 + r];
            const size_t rbase =
                obase + (size_t)(wave * 32 + qs * 16 + quad * 4 + r) * 1024;
            #pragma unroll
            for (int dt = 0; dt < 4; ++dt)
                Attn[rbase + dt * 16 + l15] = f2bf(o[qs][dt][r] * inv);
        }
}

// ---------------------------------------------------------------------------
extern "C" void kernel_launch(void* const* d_in, const int* in_sizes, int n_in,
                              void* d_out, int out_size, void* d_ws, size_t ws_size,
                              hipStream_t stream)
{
    const float* x      = (const float*)d_in[0];  // [2,2048,1024] f32
    const float* qkv_w  = (const float*)d_in[1];  // [1024,3072]
    const float* qkv_b  = (const float*)d_in[2];  // [3072]
    const float* q_nw   = (const float*)d_in[3];  // [64]
    const float* k_nw   = (const float*)d_in[4];  // [64]
    const float* proj_w = (const float*)d_in[5];  // [1024,1024]
    const float* proj_b = (const float*)d_in[6];  // [1024]
    float* out = (float*)d_out;                   // [2,2048,1024] f32

    // ws layout (48 MB):
    //  [0,8M)    Attn bf16
    //  [8,14M)   qwT bf16     [14,16M) pwT bf16
    //  [16,24M)  Xb bf16
    //  [24,32M)  Qb bf16      [32,40M) Kb bf16   [40,48M) Vt bf16
    char* ws = (char*)d_ws;
    u16* AttnB = (u16*)ws;
    u16* qwT   = (u16*)(ws + 8388608);
    u16* pwT   = (u16*)(ws + 14680064);
    u16* Xb    = (u16*)(ws + 16777216);
    u16* QbB   = (u16*)(ws + 25165824);
    u16* KbB   = (u16*)(ws + 33554432);
    u16* VtB   = (u16*)(ws + 41943040);
    (void)in_sizes; (void)n_in; (void)out_size;
    // Diagnostic guard: if ws too small, emit nothing -> absmax == max|ref|.
    if (ws_size < 50331648u) return;

    // merged prepass: cast x + transpose both weights (one launch)
    prep<<<dim3(6144), 256, 0, stream>>>(x, Xb, qkv_w, qwT, proj_w, pwT);
    // QKV GEMM with fused bias + RMSNorm + head-split/transpose epilogue
    gemm_qkv<<<dim3(3072 / 128, 4096 / 128), 256, 0, stream>>>(
        Xb, qwT, qkv_b, QbB, KbB, VtB, q_nw, k_nw);
    // flash attention v6 (double-buffered K/V, one barrier/iter)
    flash_attn_mfma<<<dim3(16, 32), 256, 0, stream>>>(QbB, KbB, VtB, AttnB);
    // out = attn @ proj_w + proj_b (f32), 64x128 tiles
    gemm_proj<<<dim3(1024 / 128, 4096 / 64), 256, 0, stream>>>(
        AttnB, pwT, proj_b, out);
}

// Round 15
// 189.758 us; speedup vs baseline: 1.0355x; 1.0355x over previous
//
#include <hip/hip_runtime.h>

typedef unsigned short u16;
typedef unsigned int u32;
typedef __bf16 bf16x8 __attribute__((ext_vector_type(8)));
typedef float f32x4 __attribute__((ext_vector_type(4)));
typedef unsigned short u16x8 __attribute__((ext_vector_type(8)));
typedef unsigned short u16x4 __attribute__((ext_vector_type(4)));

__device__ __forceinline__ float bf2f(u16 u) {
    union { unsigned int i; float f; } c; c.i = ((unsigned int)u) << 16; return c.f;
}
__device__ __forceinline__ u16 f2bf(float f) {
    union { float f; unsigned int i; } c; c.f = f;
    unsigned int r = c.i + 0x7FFFu + ((c.i >> 16) & 1u);  // RNE
    return (u16)(r >> 16);
}
__device__ __forceinline__ u16 f2bf_rtz(float f) {   // truncate: 1 VALU op
    union { float f; unsigned int i; } c; c.f = f;
    return (u16)(c.i >> 16);
}
__device__ __forceinline__ float fast_exp2(float x) {
#if __has_builtin(__builtin_amdgcn_exp2f)
    return __builtin_amdgcn_exp2f(x);   // raw v_exp_f32, no OCML fixup
#else
    return exp2f(x);
#endif
}
// async global->LDS, 16B/lane; LDS dest = wave-uniform base + lane*16
__device__ __forceinline__ void async16(const void* g, void* l) {
    __builtin_amdgcn_global_load_lds(
        (const __attribute__((address_space(1))) u32*)g,
        (__attribute__((address_space(3))) u32*)l, 16, 0, 0);
}

// ---------------------------------------------------------------------------
// Merged prepass (one launch) — measured win (R11/R12):
//  blocks [0,2048):    x f32 -> bf16 Xb (8 elems/thread)
//  blocks [2048,5120): transpose+cast qkv_w [1024][3072] -> qwT [3072][1024]
//  blocks [5120,6144): transpose+cast proj_w [1024][1024] -> pwT [1024][1024]
// ---------------------------------------------------------------------------
__global__ __launch_bounds__(256) void prep(
    const float* __restrict__ X, u16* __restrict__ Xb,
    const float* __restrict__ qkv_w, u16* __restrict__ qwT,
    const float* __restrict__ proj_w, u16* __restrict__ pwT)
{
    __shared__ float tile[32][33];
    const int blk = blockIdx.x;
    const int t = threadIdx.x;
    if (blk < 2048) {
        const size_t i = ((size_t)blk * 256 + t) * 8;
        u16x8 h;
        #pragma unroll
        for (int e = 0; e < 8; ++e) h[e] = f2bf(X[i + e]);
        *(u16x8*)&Xb[i] = h;
        return;
    }
    const float* W; u16* Th; int K, N, bx, by;
    if (blk < 5120) {
        W = qkv_w; Th = qwT; K = 1024; N = 3072;
        bx = (blk - 2048) % 96; by = (blk - 2048) / 96;
    } else {
        W = proj_w; Th = pwT; K = 1024; N = 1024;
        bx = (blk - 5120) % 32; by = (blk - 5120) / 32;
    }
    const int bk = by * 32, bn = bx * 32;
    const int tx = t & 31, ty = t >> 5;  // 32 x 8
    #pragma unroll
    for (int r = ty; r < 32; r += 8)
        tile[r][tx] = W[(size_t)(bk + r) * N + bn + tx];
    __syncthreads();
    #pragma unroll
    for (int r = ty; r < 32; r += 8)
        Th[(size_t)(bn + r) * K + bk + tx] = f2bf(tile[tx][r]);
}

// ---------------------------------------------------------------------------
// QKV GEMM (128x128 tile, BK=32, m97 staging) with fused bias + per-head
// RMSNorm -> Qb/Kb bf16 [bh][n][64] (q gets 1/8*log2e folded in) and
// V transpose -> Vt bf16 [bh][d][n].
// C/D layout: col = lane&15, row = (lane>>4)*4 + reg (verified m89/m91).
// ---------------------------------------------------------------------------
__global__ __launch_bounds__(256) void gemm_qkv(
    const u16* __restrict__ AH, const u16* __restrict__ BH,
    const float* __restrict__ bias,
    u16* __restrict__ Qb, u16* __restrict__ Kb, u16* __restrict__ Vt,
    const float* __restrict__ qw, const float* __restrict__ kw)
{
    const int K = 1024;
    __shared__ __align__(16) u16 AhT[128 * 32];
    __shared__ __align__(16) u16 BhT[128 * 32];
    const int t = threadIdx.x;
    const int bm = blockIdx.y * 128, bn = blockIdx.x * 128;
    const int wave = t >> 6, lane = t & 63;
    const int wm = (wave >> 1) * 64, wn = (wave & 1) * 64;
    const int l15 = lane & 15, quad = lane >> 4;
    const int srow = lane >> 2, scol = (lane & 3) * 8;

    f32x4 acc[4][4];
    const f32x4 zero = {0.0f, 0.0f, 0.0f, 0.0f};
    #pragma unroll
    for (int i = 0; i < 4; ++i)
        #pragma unroll
        for (int j = 0; j < 4; ++j) acc[i][j] = zero;

    for (int k0 = 0; k0 < K; k0 += 32) {
        #pragma unroll
        for (int rr = 0; rr < 2; ++rr) {
            const int r0 = (rr * 4 + wave) * 16;
            const size_t ga = (size_t)(bm + r0 + srow) * K + k0 + scol;
            const size_t gb = (size_t)(bn + r0 + srow) * K + k0 + scol;
            async16(&AH[ga], &AhT[r0 * 32]);
            async16(&BH[gb], &BhT[r0 * 32]);
        }
        __syncthreads();
        bf16x8 ah[4], bh[4];
        #pragma unroll
        for (int i = 0; i < 4; ++i)
            ah[i] = *(const bf16x8*)&AhT[(wm + i * 16 + l15) * 32 + quad * 8];
        #pragma unroll
        for (int j = 0; j < 4; ++j)
            bh[j] = *(const bf16x8*)&BhT[(wn + j * 16 + l15) * 32 + quad * 8];
        #pragma unroll
        for (int i = 0; i < 4; ++i)
            #pragma unroll
            for (int j = 0; j < 4; ++j)
                acc[i][j] = __builtin_amdgcn_mfma_f32_16x16x32_bf16(
                    ah[i], bh[j], acc[i][j], 0, 0, 0);
        __syncthreads();
    }

    // wave's 64-col group = one (section, head) pair
    const int gc0 = bn + wn;
    const int sec = gc0 >> 10;              // 0=q, 1=k, 2=v
    const int h = (gc0 & 1023) >> 6;
    const int b = bm >> 11;
    const int bhd = b * 16 + h;
    float bv[4], wj[4];
    #pragma unroll
    for (int j = 0; j < 4; ++j) {
        const int d = j * 16 + l15;
        bv[j] = bias[gc0 + d];
        wj[j] = (sec == 2) ? 0.0f : (sec ? kw[d] : qw[d] * 0.18033688011f);
    }
    if (sec < 2) {
        u16* dst = sec ? Kb : Qb;
        #pragma unroll
        for (int i = 0; i < 4; ++i) {
            float val[4][4];
            float ss[4] = {0.0f, 0.0f, 0.0f, 0.0f};
            #pragma unroll
            for (int j = 0; j < 4; ++j)
                #pragma unroll
                for (int r = 0; r < 4; ++r) {
                    val[j][r] = acc[i][j][r] + bv[j];
                    ss[r] += val[j][r] * val[j][r];
                }
            #pragma unroll
            for (int r = 0; r < 4; ++r) {
                #pragma unroll
                for (int m = 1; m < 16; m <<= 1)
                    ss[r] += __shfl_xor(ss[r], m, 64);
                const float nrm = rsqrtf(ss[r] * 0.015625f + 1e-6f);
                const int n = (bm + wm + i * 16 + quad * 4 + r) & 2047;
                const size_t rowb = ((size_t)bhd * 2048 + n) * 64;
                #pragma unroll
                for (int j = 0; j < 4; ++j)
                    dst[rowb + j * 16 + l15] = f2bf(val[j][r] * nrm * wj[j]);
            }
        }
    } else {
        #pragma unroll
        for (int i = 0; i < 4; ++i) {
            const int n0 = (bm + wm + i * 16 + quad * 4) & 2047;
            #pragma unroll
            for (int j = 0; j < 4; ++j) {
                const int d = j * 16 + l15;
                u16x4 pk;
                #pragma unroll
                for (int r = 0; r < 4; ++r)
                    pk[r] = f2bf(acc[i][j][r] + bv[j]);
                *(u16x4*)&Vt[((size_t)bhd * 64 + d) * 2048 + n0] = pk;
            }
        }
    }
}

// ---------------------------------------------------------------------------
// Proj GEMM, 64x128 tile for 512-block occupancy. Wave = 64 rows x 32 cols.
// out f32 = Attn @ pwT^T + bias.
// ---------------------------------------------------------------------------
__global__ __launch_bounds__(256) void gemm_proj(
    const u16* __restrict__ AH, const u16* __restrict__ BH,
    const float* __restrict__ bias, float* __restrict__ C)
{
    const int N = 1024, K = 1024;
    __shared__ __align__(16) u16 AhT[64 * 32];
    __shared__ __align__(16) u16 BhT[128 * 32];
    const int t = threadIdx.x;
    const int bm = blockIdx.y * 64, bn = blockIdx.x * 128;
    const int wave = t >> 6, lane = t & 63;
    const int l15 = lane & 15, quad = lane >> 4;
    const int srow = lane >> 2, scol = (lane & 3) * 8;

    f32x4 acc[4][2];
    const f32x4 zero = {0.0f, 0.0f, 0.0f, 0.0f};
    #pragma unroll
    for (int i = 0; i < 4; ++i)
        #pragma unroll
        for (int j = 0; j < 2; ++j) acc[i][j] = zero;

    for (int k0 = 0; k0 < K; k0 += 32) {
        {
            const int r0 = wave * 16;
            async16(&AH[(size_t)(bm + r0 + srow) * K + k0 + scol],
                    &AhT[r0 * 32]);
        }
        #pragma unroll
        for (int cc = 0; cc < 2; ++cc) {
            const int r0 = (wave * 2 + cc) * 16;
            async16(&BH[(size_t)(bn + r0 + srow) * K + k0 + scol],
                    &BhT[r0 * 32]);
        }
        __syncthreads();
        bf16x8 ah[4], bh[2];
        #pragma unroll
        for (int i = 0; i < 4; ++i)
            ah[i] = *(const bf16x8*)&AhT[(i * 16 + l15) * 32 + quad * 8];
        #pragma unroll
        for (int j = 0; j < 2; ++j)
            bh[j] = *(const bf16x8*)
                &BhT[(wave * 32 + j * 16 + l15) * 32 + quad * 8];
        #pragma unroll
        for (int i = 0; i < 4; ++i)
            #pragma unroll
            for (int j = 0; j < 2; ++j)
                acc[i][j] = __builtin_amdgcn_mfma_f32_16x16x32_bf16(
                    ah[i], bh[j], acc[i][j], 0, 0, 0);
        __syncthreads();
    }

    #pragma unroll
    for (int j = 0; j < 2; ++j) {
        const int col = bn + wave * 32 + j * 16 + l15;
        const float bv = bias[col];
        #pragma unroll
        for (int i = 0; i < 4; ++i) {
            const int row = bm + i * 16 + quad * 4;
            #pragma unroll
            for (int r = 0; r < 4; ++r)
                C[(size_t)(row + r) * N + col] = acc[i][j][r] + bv;
        }
    }
}

// ---------------------------------------------------------------------------
// MFMA flash attention v7 = R13 dbuf body + XCD-aware block mapping.
// Grid is 1-D 512; bh = bid & 31, qt = bid >> 5. Linear dispatch round-robins
// blocks across the 8 XCDs (id % 8), so with bh in the low bits ALL 16
// q-tile blocks of a head land on XCD bh%8 -> that XCD's L2 holds one copy
// of the head's K/V (4 heads x 512 KB = 2 MB <= 4 MB L2). Old (qt,bh) grid
// spread a head across XCDs: FETCH 69.7 MB vs ~24 MB ideal.
// Block = 4 waves x 32 q-rows = 128-row Q tile, dbuf K/V, one barrier/iter,
// Q frags direct from global, S^T = K Q^T swap (b64 P writes), static-max
// softmax (q pre-scaled by 1/8*log2e), swizzled DMA staging.
// ---------------------------------------------------------------------------
__global__ __launch_bounds__(256) void flash_attn_mfma(
    const u16* __restrict__ Qb, const u16* __restrict__ Kb,
    const u16* __restrict__ Vt, u16* __restrict__ Attn)
{
    __shared__ __align__(16) u16 Klds[2 * 64 * 64];  // swizzled [key][d], dbuf
    __shared__ __align__(16) u16 Vlds[2 * 64 * 64];  // swizzled [d][key], dbuf
    __shared__ __align__(16) u16 Plds[128][72];      // [q][key], b64 writes
    __shared__ float Lbuf[128];

    const int t = threadIdx.x;
    const int bid = blockIdx.x;
    const int bh = bid & 31;       // low bits -> same XCD for all qt of a head
    const int qt = bid >> 5;       // 0..15
    const int n0 = qt * 128;
    const size_t kbase = (size_t)bh * 2048 * 64;
    const size_t vbase = (size_t)bh * 64 * 2048;
    const int wave = t >> 6, lane = t & 63;
    const int l15 = lane & 15, quad = lane >> 4;
    const int srow8 = lane >> 3;
    const int sgrp = lane & 7;

    // Q frags direct from global (B-operand: col=q, k=d); loaded once.
    bf16x8 qf[2][2];
    #pragma unroll
    for (int qs = 0; qs < 2; ++qs) {
        const size_t qrow =
            ((size_t)bh * 2048 + n0 + wave * 32 + qs * 16 + l15) * 64;
        qf[qs][0] = *(const bf16x8*)&Qb[qrow + quad * 8];
        qf[qs][1] = *(const bf16x8*)&Qb[qrow + 32 + quad * 8];
    }

    int kofs[4][2];
    #pragma unroll
    for (int nt = 0; nt < 4; ++nt) {
        const int row = nt * 16 + l15;
        kofs[nt][0] = row * 64 + ((quad ^ (row & 7)) * 8);
        kofs[nt][1] = row * 64 + (((quad + 4) ^ (row & 7)) * 8);
    }

    f32x4 o[2][4];
    const f32x4 zero = {0.0f, 0.0f, 0.0f, 0.0f};
    #pragma unroll
    for (int qs = 0; qs < 2; ++qs)
        #pragma unroll
        for (int dt = 0; dt < 4; ++dt) o[qs][dt] = zero;
    float lsum[2] = {0.0f, 0.0f};

    // prologue: stage K/V tile 0 into buffer 0
    #pragma unroll
    for (int cc = 0; cc < 2; ++cc) {
        const int r0 = (wave + cc * 4) * 8;
        const int row = r0 + srow8;
        const int gg = sgrp ^ (row & 7);
        async16(&Kb[kbase + (size_t)row * 64 + gg * 8], &Klds[r0 * 64]);
        async16(&Vt[vbase + (size_t)row * 2048 + gg * 8], &Vlds[r0 * 64]);
    }

    for (int kt = 0; kt < 32; ++kt) {
        // Single barrier: drains the DMA for buf[kt&1] (issued one full
        // iteration ago) and fences prior-iter reads of buf[(kt+1)&1].
        __syncthreads();
        if (kt + 1 < 32) {   // prefetch next tile into the other buffer
            const int nb = ((kt + 1) & 1) * 4096;
            #pragma unroll
            for (int cc = 0; cc < 2; ++cc) {
                const int r0 = (wave + cc * 4) * 8;
                const int row = r0 + srow8;
                const int gg = sgrp ^ (row & 7);
                async16(&Kb[kbase + (size_t)((kt + 1) * 64 + row) * 64 + gg * 8],
                        &Klds[nb + r0 * 64]);
                async16(&Vt[vbase + (size_t)row * 2048 + (kt + 1) * 64 + gg * 8],
                        &Vlds[nb + r0 * 64]);
            }
        }
        const int cb = (kt & 1) * 4096;

        // S^T = K Q^T : lane gets s[qs][nt][r] = S[q=l15][key=nt*16+quad*4+r]
        f32x4 s[2][4];
        #pragma unroll
        for (int nt = 0; nt < 4; ++nt) {
            bf16x8 kf0 = *(const bf16x8*)&Klds[cb + kofs[nt][0]];
            bf16x8 kf1 = *(const bf16x8*)&Klds[cb + kofs[nt][1]];
            #pragma unroll
            for (int qs = 0; qs < 2; ++qs) {
                s[qs][nt] = zero;
                s[qs][nt] = __builtin_amdgcn_mfma_f32_16x16x32_bf16(
                    kf0, qf[qs][0], s[qs][nt], 0, 0, 0);
                s[qs][nt] = __builtin_amdgcn_mfma_f32_16x16x32_bf16(
                    kf1, qf[qs][1], s[qs][nt], 0, 0, 0);
            }
        }

        // p = exp2(s); lsum += p; pack 4 keys -> one b64 LDS write
        #pragma unroll
        for (int qs = 0; qs < 2; ++qs) {
            const int prow = wave * 32 + qs * 16 + l15;
            #pragma unroll
            for (int nt = 0; nt < 4; ++nt) {
                u16x4 pk;
                #pragma unroll
                for (int r = 0; r < 4; ++r) {
                    const float p = fast_exp2(s[qs][nt][r]);
                    lsum[qs] += p;
                    pk[r] = f2bf_rtz(p);
                }
                *(u16x4*)&Plds[prow][nt * 16 + quad * 4] = pk;
            }
        }

        // read P back in A-layout (in-wave DS order guarantees visibility)
        bf16x8 pf[2][2];
        #pragma unroll
        for (int qs = 0; qs < 2; ++qs) {
            const int prow = wave * 32 + qs * 16 + l15;
            pf[qs][0] = *(const bf16x8*)&Plds[prow][quad * 8];
            pf[qs][1] = *(const bf16x8*)&Plds[prow][quad * 8 + 32];
        }

        // O += P V : 2 qsub x 4 d-tiles x 2 ksteps
        #pragma unroll
        for (int dt = 0; dt < 4; ++dt) {
            bf16x8 vf0 = *(const bf16x8*)&Vlds[cb + kofs[dt][0]];
            bf16x8 vf1 = *(const bf16x8*)&Vlds[cb + kofs[dt][1]];
            #pragma unroll
            for (int qs = 0; qs < 2; ++qs) {
                o[qs][dt] = __builtin_amdgcn_mfma_f32_16x16x32_bf16(
                    pf[qs][0], vf0, o[qs][dt], 0, 0, 0);
                o[qs][dt] = __builtin_amdgcn_mfma_f32_16x16x32_bf16(
                    pf[qs][1], vf1, o[qs][dt], 0, 0, 0);
            }
        }
    }

    // lsum: per-lane partial for q=l15 over this quad's keys.
    // Reduce across quads (xor 16, 32), broadcast via Lbuf to O rows.
    #pragma unroll
    for (int qs = 0; qs < 2; ++qs) {
        lsum[qs] += __shfl_xor(lsum[qs], 16, 64);
        lsum[qs] += __shfl_xor(lsum[qs], 32, 64);
        if (quad == 0) Lbuf[wave * 32 + qs * 16 + l15] = lsum[qs];
    }
    const size_t obase =
        ((size_t)(bh >> 4) * 2048 + n0) * 1024 + (bh & 15) * 64;
    #pragma unroll
    for (int qs = 0; qs < 2; ++qs)
        #pragma unroll
        for (int r = 0; r < 4; ++r) {
            const float inv =
                1.0f / Lbuf[wave * 32 + qs * 16 + quad * 4 + r];
            const size_t rbase =
                obase + (size_t)(wave * 32 + qs * 16 + quad * 4 + r) * 1024;
            #pragma unroll
            for (int dt = 0; dt < 4; ++dt)
                Attn[rbase + dt * 16 + l15] = f2bf(o[qs][dt][r] * inv);
        }
}

// ---------------------------------------------------------------------------
extern "C" void kernel_launch(void* const* d_in, const int* in_sizes, int n_in,
                              void* d_out, int out_size, void* d_ws, size_t ws_size,
                              hipStream_t stream)
{
    const float* x      = (const float*)d_in[0];  // [2,2048,1024] f32
    const float* qkv_w  = (const float*)d_in[1];  // [1024,3072]
    const float* qkv_b  = (const float*)d_in[2];  // [3072]
    const float* q_nw   = (const float*)d_in[3];  // [64]
    const float* k_nw   = (const float*)d_in[4];  // [64]
    const float* proj_w = (const float*)d_in[5];  // [1024,1024]
    const float* proj_b = (const float*)d_in[6];  // [1024]
    float* out = (float*)d_out;                   // [2,2048,1024] f32

    // ws layout (48 MB):
    //  [0,8M)    Attn bf16
    //  [8,14M)   qwT bf16     [14,16M) pwT bf16
    //  [16,24M)  Xb bf16
    //  [24,32M)  Qb bf16      [32,40M) Kb bf16   [40,48M) Vt bf16
    char* ws = (char*)d_ws;
    u16* AttnB = (u16*)ws;
    u16* qwT   = (u16*)(ws + 8388608);
    u16* pwT   = (u16*)(ws + 14680064);
    u16* Xb    = (u16*)(ws + 16777216);
    u16* QbB   = (u16*)(ws + 25165824);
    u16* KbB   = (u16*)(ws + 33554432);
    u16* VtB   = (u16*)(ws + 41943040);
    (void)in_sizes; (void)n_in; (void)out_size;
    // Diagnostic guard: if ws too small, emit nothing -> absmax == max|ref|.
    if (ws_size < 50331648u) return;

    // merged prepass: cast x + transpose both weights (one launch)
    prep<<<dim3(6144), 256, 0, stream>>>(x, Xb, qkv_w, qwT, proj_w, pwT);
    // QKV GEMM with fused bias + RMSNorm + head-split/transpose epilogue
    gemm_qkv<<<dim3(3072 / 128, 4096 / 128), 256, 0, stream>>>(
        Xb, qwT, qkv_b, QbB, KbB, VtB, q_nw, k_nw);
    // flash attention v7 (R13 dbuf + XCD-aware bh-major grid)
    flash_attn_mfma<<<dim3(512), 256, 0, stream>>>(QbB, KbB, VtB, AttnB);
    // out = attn @ proj_w + proj_b (f32), 64x128 tiles
    gemm_proj<<<dim3(1024 / 128, 4096 / 64), 256, 0, stream>>>(
        AttnB, pwT, proj_b, out);
}